// Round 11
// baseline (832.726 us; speedup 1.0000x reference)
//
#include <hip/hip_runtime.h>
#include <math.h>

constexpr int B_  = 2;
constexpr int T_  = 2048;
constexpr int D_  = 512;
constexpr int NH_ = 8;
constexpr int NL_ = 256;
constexpr int HN_ = NH_ * NL_;   // 2048
constexpr int BT_ = B_ * T_;     // 4096
constexpr int NTIL = 16;         // T/128
constexpr int NTRI = NTIL * (NTIL + 1) / 2;      // 136 lower tiles
constexpr long STILE = (long)NTRI * 128 * 128;   // elems per (b,h) S slice

typedef __bf16 v8bf __attribute__((ext_vector_type(8)));
typedef float  v4f  __attribute__((ext_vector_type(4)));
typedef unsigned short us8 __attribute__((ext_vector_type(8)));

__device__ inline unsigned short f2b(float f) {
    union { float f; unsigned u; } v{f};
    unsigned r = v.u + 0x7FFF + ((v.u >> 16) & 1);   // rtne
    return (unsigned short)(r >> 16);
}
__device__ inline float b2f(unsigned short u) {
    union { unsigned u; float f; } v{(unsigned)u << 16};
    return v.f;
}

// async 16B global->LDS (per-lane gaddr; LDS dest = wave-uniform base + lane*16)
__device__ __forceinline__ void g2l16(const void* g, void* l) {
    __builtin_amdgcn_global_load_lds(
        (const __attribute__((address_space(1))) void*)g,
        (__attribute__((address_space(3))) void*)l, 16, 0, 0);
}

// ===========================================================================
// 128x128-tile core (s_gemm): 4 waves 2x2, 4x4 MFMA/wave.
#define TILE_IDS                                              \
    int tid = threadIdx.x;                                    \
    int lane = tid & 63, wid = tid >> 6;                      \
    int wm = (wid & 1) * 64, wn = (wid >> 1) * 64;            \
    int ln16 = lane & 15, q = lane >> 4;                      \
    int e0 = (wid * 2 + 0) * 512 + lane * 8;                  \
    int e1 = (wid * 2 + 1) * 512 + lane * 8;                  \
    int r0 = e0 >> 5, c0 = e0 & 31, r1 = e1 >> 5, c1 = e1 & 31;

#define TILE_MFMA(As, Bs)                                     \
    {                                                         \
        v8bf af[4], bfr[4];                                   \
        _Pragma("unroll")                                     \
        for (int r = 0; r < 4; ++r)                           \
            af[r] = *(const v8bf*)&As[wm + r * 16 + ln16][q * 8]; \
        _Pragma("unroll")                                     \
        for (int c = 0; c < 4; ++c)                           \
            bfr[c] = *(const v8bf*)&Bs[wn + c * 16 + ln16][q * 8]; \
        _Pragma("unroll")                                     \
        for (int r = 0; r < 4; ++r)                           \
            _Pragma("unroll")                                 \
            for (int c = 0; c < 4; ++c)                       \
                acc[r][c] = __builtin_amdgcn_mfma_f32_16x16x32_bf16( \
                    af[r], bfr[c], acc[r][c], 0, 0, 0);       \
    }

// ===========================================================================
// 64x128-tile core (generic GEMM): 4 waves n-split 32, 4x2 MFMA.
#define T64_IDS                                               \
    int tid = threadIdx.x;                                    \
    int lane = tid & 63, wid = tid >> 6;                      \
    int wn = wid * 32;                                        \
    int ln16 = lane & 15, q = lane >> 4;                      \
    int srl = lane >> 2, scl = (lane & 3) * 8;

#define T64_STAGE(Ab, lda, Bb, ldb, k0)                       \
    _Pragma("unroll")                                         \
    for (int ci = 0; ci < 3; ++ci) {                          \
        int c = wid * 3 + ci;                                 \
        if (c < 4) {                                          \
            int r = c * 16 + srl;                             \
            g2l16(Ab + (long)r * lda + (k0) + scl, (char*)As + c * 1024); \
        } else {                                              \
            int r = (c - 4) * 16 + srl;                       \
            g2l16(Bb + (long)r * ldb + (k0) + scl, (char*)Bs + (c - 4) * 1024); \
        }                                                     \
    }

#define T64_MFMA(As, Bs)                                      \
    {                                                         \
        v8bf af[4], bf2[2];                                   \
        _Pragma("unroll")                                     \
        for (int r = 0; r < 4; ++r)                           \
            af[r] = *(const v8bf*)&As[r * 16 + ln16][q * 8];  \
        _Pragma("unroll")                                     \
        for (int c = 0; c < 2; ++c)                           \
            bf2[c] = *(const v8bf*)&Bs[wn + c * 16 + ln16][q * 8]; \
        _Pragma("unroll")                                     \
        for (int r = 0; r < 4; ++r)                           \
            _Pragma("unroll")                                 \
            for (int c = 0; c < 2; ++c)                       \
                acc[r][c] = __builtin_amdgcn_mfma_f32_16x16x32_bf16( \
                    af[r], bf2[c], acc[r][c], 0, 0, 0);       \
    }

// ---------------------------------------------------------------------------
// Generic 64-row bf16 GEMM: C[M,N] = A[M,K] @ Bt[N,K]^T, z-batched (split-K
// via sA/sB element offsets + sC output slices; per-head via matrix strides).
template <bool RELU, bool MUL, bool BF16OUT>
__global__ __launch_bounds__(256) void gemm64(
    const unsigned short* __restrict__ A, int lda, long sA,
    const unsigned short* __restrict__ Bt, int ldb, long sB,
    void* __restrict__ Cv, int ldc, long sC,
    const unsigned short* __restrict__ mulp, int M, int N, int K) {
    int m0 = blockIdx.y * 64, n0 = blockIdx.x * 128, z = blockIdx.z;
    __shared__ unsigned short As[64][32];    // 4 KB
    __shared__ unsigned short Bs[128][32];   // 8 KB
    const unsigned short* Ab = A  + (long)z * sA + (long)m0 * lda;
    const unsigned short* Bb = Bt + (long)z * sB + (long)n0 * ldb;
    T64_IDS
    v4f acc[4][2] = {};
    for (int k0 = 0; k0 < K; k0 += 32) {
        T64_STAGE(Ab, lda, Bb, ldb, k0)
        __syncthreads();
        T64_MFMA(As, Bs)
        __syncthreads();
    }
    float* Cf = (float*)Cv;
    unsigned short* Cb = (unsigned short*)Cv;
    long zoff = (long)z * sC;
    #pragma unroll
    for (int r = 0; r < 4; ++r)
        #pragma unroll
        for (int c = 0; c < 2; ++c)
            #pragma unroll
            for (int e = 0; e < 4; ++e) {
                int row = m0 + r * 16 + q * 4 + e;
                int col = n0 + wn + c * 16 + ln16;
                float v = acc[r][c][e];
                if (RELU) v = fmaxf(v, 0.f);
                long idx = zoff + (long)row * ldc + col;
                if (MUL) v *= b2f(mulp[idx]);
                if (BF16OUT) Cb[idx] = f2b(v);
                else         Cf[idx] = v;
            }
}

// ---------------------------------------------------------------------------
// S-GEMM: packed-triangular scores (128-tile).  grid (16 z, NTRI);
// z in blockIdx.x so L%8 = z%8 pins each z's QR slice (1 MB) to one XCD.
__global__ __launch_bounds__(256) void s_gemm(const unsigned short* __restrict__ qr,
                                              unsigned short* __restrict__ Sp) {
    int x = blockIdx.y, z = blockIdx.x;
    int i = 0, rem = x;
    while (rem >= i + 1) { rem -= i + 1; ++i; }
    int j = rem;                       // tile (i, j), j <= i
    const unsigned short* zb = qr + (long)z * T_ * NL_;
    const unsigned short* Ab = zb + (long)(i * 128) * NL_;
    const unsigned short* Bb = zb + (long)(j * 128) * NL_;
    __shared__ unsigned short As[128][32];
    __shared__ unsigned short Bs[128][32];
    TILE_IDS
    v4f acc[4][4] = {};
    for (int k0 = 0; k0 < NL_; k0 += 32) {
        g2l16(Ab + (long)r0 * NL_ + k0 + c0, (char*)As + (wid * 2 + 0) * 1024);
        g2l16(Ab + (long)r1 * NL_ + k0 + c1, (char*)As + (wid * 2 + 1) * 1024);
        g2l16(Bb + (long)r0 * NL_ + k0 + c0, (char*)Bs + (wid * 2 + 0) * 1024);
        g2l16(Bb + (long)r1 * NL_ + k0 + c1, (char*)Bs + (wid * 2 + 1) * 1024);
        __syncthreads();
        TILE_MFMA(As, Bs)
        __syncthreads();
    }
    unsigned short* ob = Sp + (long)z * STILE + (long)x * 16384;
    bool diag = (i == j);
    #pragma unroll
    for (int r = 0; r < 4; ++r)
        #pragma unroll
        for (int c = 0; c < 4; ++c)
            #pragma unroll
            for (int e = 0; e < 4; ++e) {
                int row = wm + r * 16 + q * 4 + e;
                int col = wn + c * 16 + ln16;
                float v = acc[r][c][e];
                if (diag && row <= col) v = 0.f;   // strict causal
                ob[row * 128 + col] = f2b(v);
            }
}

// ---------------------------------------------------------------------------
// PX-DIRECT: yKV = LN(S @ xs).  Barrier-free K-loop: MFMA A/B fragments are
// loaded straight from global (Sp row-major tiles / xsT K-major) with
// global_load_dwordx4 — no LDS staging, no __syncthreads until the LN
// epilogue.  Latency hidden by per-wave outstanding loads + 2-waves/SIMD
// interleave.  A-frags are 4x redundant across waves (L2 absorbs).
// 1D grid 512: p = L&7 -> XCD; z = 2p | (s&1) (one b, two heads per XCD,
// X 2MB L2-pinned); strip map M[idx] balances CU pairs (s, s+32) to exactly
// 68 rounds.  Block owns 64 rows x full D=512 -> LN fused (1 KB LDS).
__device__ inline int seq0v(int i) {       // 16,1,15,2,14,3,... for i=0..15
    return (i & 1) ? ((i + 1) >> 1) : (16 - (i >> 1));
}
__global__ __launch_bounds__(256, 2) void px_direct(
    const unsigned short* __restrict__ Sp,
    const unsigned short* __restrict__ xsT,
    unsigned short* __restrict__ ykv) {
    int L = blockIdx.x;
    int p = L & 7, s = L >> 3;
    int z = (p << 1) | (s & 1);
    int idx = s >> 1;
    int v = (idx < 16) ? seq0v(idx) : (17 - seq0v(idx - 16));
    int ti = v - 1;                          // 128-tile row 0..15
    int my = 2 * ti + (idx < 16 ? 0 : 1);    // 64-row strip 0..31
    int b = z >> 3, h = z & 7;
    const unsigned short* Ab = Sp + (long)z * STILE +
                               (long)(ti * (ti + 1) / 2) * 16384 +
                               (long)(my & 1) * 64 * 128;
    const unsigned short* Xb = xsT + (long)b * D_ * T_;
    int tid = threadIdx.x;
    int lane = tid & 63, wid = tid >> 6;
    int ln16 = lane & 15, q = lane >> 4;
    v4f yacc[4][8] = {};
    int rounds = (ti + 1) * 4;
    for (int r = 0; r < rounds; ++r) {
        const unsigned short* At = Ab + ((long)(r >> 2) << 14);
        int kk = (r & 3) * 32;
        int k0 = r * 32;
        v8bf af[4], xf[8];
        #pragma unroll
        for (int m = 0; m < 4; ++m)
            af[m] = *(const v8bf*)&At[(m * 16 + ln16) * 128 + kk + q * 8];
        const unsigned short* Xt = Xb + k0 + q * 8;
        #pragma unroll
        for (int n = 0; n < 8; ++n)
            xf[n] = *(const v8bf*)&Xt[(long)(wid * 128 + n * 16 + ln16) * T_];
        #pragma unroll
        for (int m = 0; m < 4; ++m)
            #pragma unroll
            for (int n = 0; n < 8; ++n)
                yacc[m][n] = __builtin_amdgcn_mfma_f32_16x16x32_bf16(
                    af[m], xf[n], yacc[m][n], 0, 0, 0);
    }

    // ---- fused LayerNorm (two-pass, centered) over the 512-wide rows ----
    __shared__ float red[64 * 4];            // [row][wave]
    float mu[4][4], inv[4][4];
    #pragma unroll
    for (int m = 0; m < 4; ++m)
        #pragma unroll
        for (int e = 0; e < 4; ++e) {
            float pr = 0.f;
            #pragma unroll
            for (int n = 0; n < 8; ++n) pr += yacc[m][n][e];
            #pragma unroll
            for (int off = 1; off < 16; off <<= 1) pr += __shfl_xor(pr, off, 64);
            if (ln16 == 0) red[(m * 16 + q * 4 + e) * 4 + wid] = pr;
        }
    __syncthreads();
    #pragma unroll
    for (int m = 0; m < 4; ++m)
        #pragma unroll
        for (int e = 0; e < 4; ++e) {
            int rl = (m * 16 + q * 4 + e) * 4;
            mu[m][e] = (red[rl] + red[rl + 1] + red[rl + 2] + red[rl + 3]) *
                       (1.0f / 512.0f);
        }
    __syncthreads();
    #pragma unroll
    for (int m = 0; m < 4; ++m)
        #pragma unroll
        for (int e = 0; e < 4; ++e) {
            float pr = 0.f;
            #pragma unroll
            for (int n = 0; n < 8; ++n) {
                float d = yacc[m][n][e] - mu[m][e];
                pr += d * d;
            }
            #pragma unroll
            for (int off = 1; off < 16; off <<= 1) pr += __shfl_xor(pr, off, 64);
            if (ln16 == 0) red[(m * 16 + q * 4 + e) * 4 + wid] = pr;
        }
    __syncthreads();
    #pragma unroll
    for (int m = 0; m < 4; ++m)
        #pragma unroll
        for (int e = 0; e < 4; ++e) {
            int rl = (m * 16 + q * 4 + e) * 4;
            float var = (red[rl] + red[rl + 1] + red[rl + 2] + red[rl + 3]) *
                        (1.0f / 512.0f);
            inv[m][e] = rsqrtf(var + 1e-5f);
        }
    #pragma unroll
    for (int m = 0; m < 4; ++m)
        #pragma unroll
        for (int n = 0; n < 8; ++n)
            #pragma unroll
            for (int e = 0; e < 4; ++e) {
                int t = my * 64 + m * 16 + q * 4 + e;
                int d = wid * 128 + n * 16 + ln16;
                float vv = (yacc[m][n][e] - mu[m][e]) * inv[m][e];
                ykv[((long)h * BT_ + (long)b * T_ + t) * D_ + d] = f2b(vv);
            }
}

// ---------------------------------------------------------------------------
// Transpose + cast fp32 -> bf16: out[Cc][R] = (bf16) in[R][Cc], batched.
__global__ __launch_bounds__(256) void trans_cast(
    const float* __restrict__ in, long sIn, unsigned short* __restrict__ out,
    long sOut, int R, int Cc) {
    __shared__ float tl[32][33];
    int z = blockIdx.z;
    int r0 = blockIdx.y * 32, c0 = blockIdx.x * 32;
    int tx = threadIdx.x & 31, ty = threadIdx.x >> 5;
    const float* ip = in + (long)z * sIn;
    unsigned short* op = out + (long)z * sOut;
    #pragma unroll
    for (int j = 0; j < 4; ++j)
        tl[ty + j * 8][tx] = ip[(long)(r0 + ty + j * 8) * Cc + c0 + tx];
    __syncthreads();
    #pragma unroll
    for (int j = 0; j < 4; ++j)
        op[(long)(c0 + ty + j * 8) * R + r0 + tx] = f2b(tl[tx][ty + j * 8]);
}

// fp32 -> bf16 elementwise (n multiple of 1024)
__global__ __launch_bounds__(256) void cast_b(const float* __restrict__ in,
                                              unsigned short* __restrict__ out) {
    long i = ((long)blockIdx.x * 256 + threadIdx.x) * 4;
    float4 v = *(const float4*)&in[i];
    ushort4 o;
    o.x = f2b(v.x); o.y = f2b(v.y); o.z = f2b(v.z); o.w = f2b(v.w);
    *(ushort4*)&out[i] = o;
}

// out = t0+t1+t2+t3 + bias (4 split-K slices, rows of 512)
__global__ __launch_bounds__(256) void add_out4(const float* __restrict__ t,
                                                long slice,
                                                const float* __restrict__ bias,
                                                float* __restrict__ o) {
    long i = ((long)blockIdx.x * 256 + threadIdx.x) * 4;
    float4 v0 = *(const float4*)&t[i];
    float4 v1 = *(const float4*)&t[i + slice];
    float4 v2 = *(const float4*)&t[i + 2 * slice];
    float4 v3 = *(const float4*)&t[i + 3 * slice];
    float4 bv = *(const float4*)&bias[i & 511];
    float4 r;
    r.x = v0.x + v1.x + v2.x + v3.x + bv.x;
    r.y = v0.y + v1.y + v2.y + v3.y + bv.y;
    r.z = v0.z + v1.z + v2.z + v3.z + bv.z;
    r.w = v0.w + v1.w + v2.w + v3.w + bv.w;
    *(float4*)&o[i] = r;
}

// ---------------------------------------------------------------------------
// RoPE: xsp [BT][HN] bf16 -> qr [B][NH][T][NL] bf16 (head-outer layout).
__global__ __launch_bounds__(256) void rope_b(const unsigned short* __restrict__ xsp,
                                              unsigned short* __restrict__ qr) {
    long i = (long)blockIdx.x * 256 + threadIdx.x;  // group of 4 pairs
    int g = (int)(i & 255);
    long row = i >> 8;
    int h = g >> 5, n8 = g & 31;
    long b = row >> 11;
    int t = (int)(row & (T_ - 1));
    us8 u = *(const us8*)&xsp[row * HN_ + (long)g * 8];
    us8 o;
    #pragma unroll
    for (int p = 0; p < 4; ++p) {
        int n2 = n8 * 4 + p;
        float f = exp2f(-(float)n2 * 0.125f) * (float)(1.0 / (2.0 * M_PI));
        float ph = (float)t * f;
        ph = (ph - floorf(ph)) * (float)(2.0 * M_PI);
        float s, c;
        __sincosf(ph, &s, &c);
        float x0 = b2f(u[2 * p]), x1 = b2f(u[2 * p + 1]);
        o[2 * p]     = f2b(x0 * c - x1 * s);
        o[2 * p + 1] = f2b(x1 * c + x0 * s);
    }
    long ob = (((b * NH_ + h) * T_ + t) * NL_) + (long)n8 * 8;
    *(us8*)&qr[ob] = o;
}

// ---------------------------------------------------------------------------
// LayerNorm helpers (rows of 512, 256 threads, float2 per thread)
__device__ inline float2 block_reduce2(float a, float b) {
    __shared__ float sa[4], sb[4];
    #pragma unroll
    for (int off = 32; off; off >>= 1) {
        a += __shfl_down(a, off, 64);
        b += __shfl_down(b, off, 64);
    }
    __syncthreads();
    int w = threadIdx.x >> 6;
    if ((threadIdx.x & 63) == 0) { sa[w] = a; sb[w] = b; }
    __syncthreads();
    return make_float2(sa[0] + sa[1] + sa[2] + sa[3],
                       sb[0] + sb[1] + sb[2] + sb[3]);
}
__device__ inline float2 ln_pair(float2 v) {
    float2 s = block_reduce2(v.x + v.y, 0.f);
    float mu = s.x * (1.0f / 512.0f);
    float dx = v.x - mu, dy = v.y - mu;
    float2 q = block_reduce2(dx * dx + dy * dy, 0.f);
    float inv = rsqrtf(q.x * (1.0f / 512.0f) + 1e-5f);
    return make_float2(dx * inv, dy * inv);
}

// LN(sum of 4 slices + bias) -> fp32 + bf16
__global__ __launch_bounds__(256) void ln_dual4(const float* __restrict__ t,
                                                long slice,
                                                const float* __restrict__ bias,
                                                float* __restrict__ outf,
                                                unsigned short* __restrict__ outb) {
    long row = blockIdx.x;
    int c = threadIdx.x * 2;
    long i = row * 512 + c;
    float2 v0 = *(const float2*)&t[i];
    float2 v1 = *(const float2*)&t[i + slice];
    float2 v2 = *(const float2*)&t[i + 2 * slice];
    float2 v3 = *(const float2*)&t[i + 3 * slice];
    float2 bv = *(const float2*)&bias[c];
    float2 v = make_float2(v0.x + v1.x + v2.x + v3.x + bv.x,
                           v0.y + v1.y + v2.y + v3.y + bv.y);
    float2 o = ln_pair(v);
    *(float2*)&outf[i] = o;
    ushort2 ob; ob.x = f2b(o.x); ob.y = f2b(o.y);
    *(ushort2*)&outb[i] = ob;
}

// xs_next = LN(x_res + LN(sum of 4 ymlp slices)) -> fp32 + bf16
__global__ __launch_bounds__(256) void combine_dual4(
    const float* __restrict__ t, long slice, const float* __restrict__ xres,
    float* __restrict__ outf, unsigned short* __restrict__ outb) {
    long row = blockIdx.x;
    int c = threadIdx.x * 2;
    long i = row * 512 + c;
    float2 v0 = *(const float2*)&t[i];
    float2 v1 = *(const float2*)&t[i + slice];
    float2 v2 = *(const float2*)&t[i + 2 * slice];
    float2 v3 = *(const float2*)&t[i + 3 * slice];
    float2 y = make_float2(v0.x + v1.x + v2.x + v3.x,
                           v0.y + v1.y + v2.y + v3.y);
    float2 l = ln_pair(y);
    float2 r = *(const float2*)&xres[i];
    float2 z = make_float2(r.x + l.x, r.y + l.y);
    float2 o = ln_pair(z);
    *(float2*)&outf[i] = o;
    ushort2 ob; ob.x = f2b(o.x); ob.y = f2b(o.y);
    *(ushort2*)&outb[i] = ob;
}

// ---------------------------------------------------------------------------
extern "C" void kernel_launch(void* const* d_in, const int* in_sizes, int n_in,
                              void* d_out, int out_size, void* d_ws,
                              size_t ws_size, hipStream_t stream) {
    const float* x      = (const float*)d_in[0];
    const float* w_in   = (const float*)d_in[1];
    const float* b_in   = (const float*)d_in[2];
    const float* enc    = (const float*)d_in[3];
    const float* enc_v  = (const float*)d_in[4];
    const float* dec    = (const float*)d_in[5];
    const float* head_w = (const float*)d_in[6];
    const float* head_b = (const float*)d_in[7];
    float* out = (float*)d_out;

    // ---- workspace (~209 MB) ----
    char* w = (char*)d_ws;
    auto alloc = [&](size_t bytes) { void* p = (void*)w; w += bytes; return p; };
    unsigned short* w_inT = (unsigned short*)alloc((size_t)512 * 512 * 2);
    unsigned short* headT = (unsigned short*)alloc((size_t)512 * 512 * 2);
    unsigned short* encT  = (unsigned short*)alloc((size_t)NH_ * NL_ * D_ * 2);
    unsigned short* encvT = (unsigned short*)alloc((size_t)NH_ * NL_ * D_ * 2);
    unsigned short* decT  = (unsigned short*)alloc((size_t)D_ * HN_ * 2);
    unsigned short* xb    = (unsigned short*)alloc((size_t)BT_ * D_ * 2);
    float*          tmp   = (float*)alloc((size_t)4 * BT_ * D_ * 4);  // 4 K-slices
    float*          xsf0  = (float*)alloc((size_t)BT_ * D_ * 4);
    float*          xsf1  = (float*)alloc((size_t)BT_ * D_ * 4);
    unsigned short* xs_b  = (unsigned short*)alloc((size_t)BT_ * D_ * 2);
    unsigned short* xsT   = (unsigned short*)alloc((size_t)B_ * D_ * T_ * 2);
    unsigned short* xsp   = (unsigned short*)alloc((size_t)BT_ * HN_ * 2);
    unsigned short* qrh   = (unsigned short*)alloc((size_t)BT_ * HN_ * 2);
    unsigned short* Sp    = (unsigned short*)alloc((size_t)16 * STILE * 2);
    unsigned short* ykv   = (unsigned short*)alloc((size_t)NH_ * BT_ * D_ * 2);
    const long SL = (long)BT_ * D_;   // split-K slice stride (elements)

    // ---- prep ----
    cast_b<<<BT_ * D_ / 1024, 256, 0, stream>>>(x, xb);
    trans_cast<<<dim3(16, 16, 1), 256, 0, stream>>>(w_in, 0, w_inT, 0, 512, 512);
    trans_cast<<<dim3(16, 16, 1), 256, 0, stream>>>(head_w, 0, headT, 0, 512, 512);
    trans_cast<<<dim3(8, 16, 8), 256, 0, stream>>>(enc, (long)D_ * NL_, encT,
                                                   (long)NL_ * D_, D_, NL_);
    trans_cast<<<dim3(8, 16, 8), 256, 0, stream>>>(enc_v, (long)D_ * NL_, encvT,
                                                   (long)NL_ * D_, D_, NL_);
    trans_cast<<<dim3(16, 64, 1), 256, 0, stream>>>(dec, 0, decT, 0, HN_, D_);

    // ---- xs = LN(x @ w_in + b_in)  (split-K=4, K=128/slice) ----
    gemm64<false, false, false>
        <<<dim3(4, 64, 4), 256, 0, stream>>>(xb, D_, 128, w_inT, D_, 128, tmp,
                                             D_, SL, nullptr, BT_, D_, 128);
    ln_dual4<<<BT_, 256, 0, stream>>>(tmp, SL, b_in, xsf0, xs_b);
    trans_cast<<<dim3(16, 64, 2), 256, 0, stream>>>(xsf0, (long)T_ * D_, xsT,
                                                    (long)D_ * T_, T_, D_);

    float* xin = xsf0;
    float* xout = xsf1;
    for (int l = 0; l < 3; ++l) {
        // x_sparse = relu(xs @ enc) -> bf16 [BT][HN]
        gemm64<true, false, true>
            <<<dim3(16, 64, 1), 256, 0, stream>>>(
                xs_b, D_, 0, encT, D_, 0, xsp, HN_, 0, nullptr, BT_, HN_, D_);
        // QR = rope(x_sparse) -> [B][NH][T][NL]
        rope_b<<<BT_ * HN_ / 8 / 256, 256, 0, stream>>>(xsp, qrh);
        // S = strict_tril(QR QR^T), packed tiles, z XCD-pinned
        s_gemm<<<dim3(16, NTRI), 256, 0, stream>>>(qrh, Sp);
        // yKV = LN(S @ xs) — barrier-free direct-load px, balanced 1D grid
        px_direct<<<512, 256, 0, stream>>>(Sp, xsT, ykv);
        // xy = relu(yKV[h] @ enc_v[h]) * x_sparse — per-head batched
        gemm64<true, true, true>
            <<<dim3(2, 64, 8), 256, 0, stream>>>(
                ykv, D_, (long)BT_ * D_, encvT, D_, (long)NL_ * D_, xsp, HN_,
                NL_, xsp, BT_, NL_, D_);
        // yMLP = xy @ decoder  (split-K=4, K=512/slice) -> fp32 slices
        gemm64<false, false, false>
            <<<dim3(4, 64, 4), 256, 0, stream>>>(
                xsp, HN_, 512, decT, HN_, 512, tmp, D_, SL, nullptr, BT_, D_,
                512);
        // xs = LN(x_res + LN(yMLP))
        combine_dual4<<<BT_, 256, 0, stream>>>(tmp, SL, xin, xout, xs_b);
        trans_cast<<<dim3(16, 64, 2), 256, 0, stream>>>(xout, (long)T_ * D_,
                                                        xsT, (long)D_ * T_, T_,
                                                        D_);
        float* t = xin; xin = xout; xout = t;
    }

    // logits = xs @ head_w + head_b  (split-K=4)
    gemm64<false, false, false>
        <<<dim3(4, 64, 4), 256, 0, stream>>>(xs_b, D_, 128, headT, D_, 128, tmp,
                                             D_, SL, nullptr, BT_, D_, 128);
    add_out4<<<BT_ * 512 / 1024, 256, 0, stream>>>(tmp, SL, head_b, out);
}

// Round 12
// 710.504 us; speedup vs baseline: 1.1720x; 1.1720x over previous
//
#include <hip/hip_runtime.h>
#include <math.h>

constexpr int B_  = 2;
constexpr int T_  = 2048;
constexpr int D_  = 512;
constexpr int NH_ = 8;
constexpr int NL_ = 256;
constexpr int HN_ = NH_ * NL_;   // 2048
constexpr int BT_ = B_ * T_;     // 4096

typedef __bf16 v8bf __attribute__((ext_vector_type(8)));
typedef float  v4f  __attribute__((ext_vector_type(4)));
typedef unsigned short us8 __attribute__((ext_vector_type(8)));

__device__ inline unsigned short f2b(float f) {
    union { float f; unsigned u; } v{f};
    unsigned r = v.u + 0x7FFF + ((v.u >> 16) & 1);   // rtne
    return (unsigned short)(r >> 16);
}
__device__ inline float b2f(unsigned short u) {
    union { unsigned u; float f; } v{(unsigned)u << 16};
    return v.f;
}

// async 16B global->LDS (per-lane gaddr; LDS dest = wave-uniform base + lane*16)
__device__ __forceinline__ void g2l16(const void* g, void* l) {
    __builtin_amdgcn_global_load_lds(
        (const __attribute__((address_space(1))) void*)g,
        (__attribute__((address_space(3))) void*)l, 16, 0, 0);
}

// ===========================================================================
// 128x128-tile core: 4 waves 2x2, 4x4 MFMA/wave.
#define TILE_IDS                                              \
    int tid = threadIdx.x;                                    \
    int lane = tid & 63, wid = tid >> 6;                      \
    int wm = (wid & 1) * 64, wn = (wid >> 1) * 64;            \
    int ln16 = lane & 15, q = lane >> 4;                      \
    int e0 = (wid * 2 + 0) * 512 + lane * 8;                  \
    int e1 = (wid * 2 + 1) * 512 + lane * 8;                  \
    int r0 = e0 >> 5, c0 = e0 & 31, r1 = e1 >> 5, c1 = e1 & 31;

#define TILE_MFMA(As, Bs)                                     \
    {                                                         \
        v8bf af[4], bfr[4];                                   \
        _Pragma("unroll")                                     \
        for (int r = 0; r < 4; ++r)                           \
            af[r] = *(const v8bf*)&As[wm + r * 16 + ln16][q * 8]; \
        _Pragma("unroll")                                     \
        for (int c = 0; c < 4; ++c)                           \
            bfr[c] = *(const v8bf*)&Bs[wn + c * 16 + ln16][q * 8]; \
        _Pragma("unroll")                                     \
        for (int r = 0; r < 4; ++r)                           \
            _Pragma("unroll")                                 \
            for (int c = 0; c < 4; ++c)                       \
                acc[r][c] = __builtin_amdgcn_mfma_f32_16x16x32_bf16( \
                    af[r], bfr[c], acc[r][c], 0, 0, 0);       \
    }

// ===========================================================================
// 64x128-tile core: 4 waves n-split 32, 4x2 MFMA.
#define T64_IDS                                               \
    int tid = threadIdx.x;                                    \
    int lane = tid & 63, wid = tid >> 6;                      \
    int wn = wid * 32;                                        \
    int ln16 = lane & 15, q = lane >> 4;                      \
    int srl = lane >> 2, scl = (lane & 3) * 8;

#define T64_STAGE(Ab, lda, Bb, ldb, k0)                       \
    _Pragma("unroll")                                         \
    for (int ci = 0; ci < 3; ++ci) {                          \
        int c = wid * 3 + ci;                                 \
        if (c < 4) {                                          \
            int r = c * 16 + srl;                             \
            g2l16(Ab + (long)r * lda + (k0) + scl, (char*)As + c * 1024); \
        } else {                                              \
            int r = (c - 4) * 16 + srl;                       \
            g2l16(Bb + (long)r * ldb + (k0) + scl, (char*)Bs + (c - 4) * 1024); \
        }                                                     \
    }

#define T64_MFMA(As, Bs)                                      \
    {                                                         \
        v8bf af[4], bf2[2];                                   \
        _Pragma("unroll")                                     \
        for (int r = 0; r < 4; ++r)                           \
            af[r] = *(const v8bf*)&As[r * 16 + ln16][q * 8];  \
        _Pragma("unroll")                                     \
        for (int c = 0; c < 2; ++c)                           \
            bf2[c] = *(const v8bf*)&Bs[wn + c * 16 + ln16][q * 8]; \
        _Pragma("unroll")                                     \
        for (int r = 0; r < 4; ++r)                           \
            _Pragma("unroll")                                 \
            for (int c = 0; c < 2; ++c)                       \
                acc[r][c] = __builtin_amdgcn_mfma_f32_16x16x32_bf16( \
                    af[r], bf2[c], acc[r][c], 0, 0, 0);       \
    }

// ---------------------------------------------------------------------------
// Generic 64-row bf16 GEMM: C[M,N] = A[M,K] @ Bt[N,K]^T, z-batched.
template <bool RELU, bool MUL, bool BF16OUT>
__global__ __launch_bounds__(256) void gemm64(
    const unsigned short* __restrict__ A, int lda, long sA,
    const unsigned short* __restrict__ Bt, int ldb, long sB,
    void* __restrict__ Cv, int ldc, long sC,
    const unsigned short* __restrict__ mulp, int M, int N, int K) {
    int m0 = blockIdx.y * 64, n0 = blockIdx.x * 128, z = blockIdx.z;
    __shared__ unsigned short As[64][32];    // 4 KB
    __shared__ unsigned short Bs[128][32];   // 8 KB
    const unsigned short* Ab = A  + (long)z * sA + (long)m0 * lda;
    const unsigned short* Bb = Bt + (long)z * sB + (long)n0 * ldb;
    T64_IDS
    v4f acc[4][2] = {};
    for (int k0 = 0; k0 < K; k0 += 32) {
        T64_STAGE(Ab, lda, Bb, ldb, k0)
        __syncthreads();
        T64_MFMA(As, Bs)
        __syncthreads();
    }
    float* Cf = (float*)Cv;
    unsigned short* Cb = (unsigned short*)Cv;
    long zoff = (long)z * sC;
    #pragma unroll
    for (int r = 0; r < 4; ++r)
        #pragma unroll
        for (int c = 0; c < 2; ++c)
            #pragma unroll
            for (int e = 0; e < 4; ++e) {
                int row = m0 + r * 16 + q * 4 + e;
                int col = n0 + wn + c * 16 + ln16;
                float v = acc[r][c][e];
                if (RELU) v = fmaxf(v, 0.f);
                long idx = zoff + (long)row * ldc + col;
                if (MUL) v *= b2f(mulp[idx]);
                if (BF16OUT) Cb[idx] = f2b(v);
                else         Cf[idx] = v;
            }
}

// ---------------------------------------------------------------------------
// CT-GEMM (linear-attn state tiles): Ct[z][j][d][n] = X_j^T @ QR_j, i.e.
// Ct[d][n] = sum_{t in tile j} xsT[b][d][t] * qrT[z][n][t].  M=512(d),
// N=256(n), K=128(t).  grid (16 z, 2 nt, 128 = j*8+mt); z fastest -> XCD pin.
__global__ __launch_bounds__(256) void ct_gemm(
    const unsigned short* __restrict__ xsT,   // [B][D][T]
    const unsigned short* __restrict__ qrT,   // [B*NH][NL][T]
    unsigned short* __restrict__ Ct) {        // [z*16+j][512][256]
    int z = blockIdx.x, nt = blockIdx.y;
    int j = blockIdx.z >> 3, mt = blockIdx.z & 7;
    int b = z >> 3;
    const unsigned short* Ab =
        xsT + (long)b * D_ * T_ + (long)(mt * 64) * T_ + j * 128;
    const unsigned short* Bb =
        qrT + (long)z * NL_ * T_ + (long)(nt * 128) * T_ + j * 128;
    __shared__ unsigned short As[64][32];
    __shared__ unsigned short Bs[128][32];
    T64_IDS
    v4f acc[4][2] = {};
    for (int k0 = 0; k0 < 128; k0 += 32) {
        T64_STAGE(Ab, T_, Bb, T_, k0)
        __syncthreads();
        T64_MFMA(As, Bs)
        __syncthreads();
    }
    unsigned short* ob = Ct + ((long)z * 16 + j) * 512 * 256;
    #pragma unroll
    for (int r = 0; r < 4; ++r)
        #pragma unroll
        for (int c = 0; c < 2; ++c)
            #pragma unroll
            for (int e = 0; e < 4; ++e) {
                int row = mt * 64 + r * 16 + q * 4 + e;           // d
                int col = nt * 128 + wn + c * 16 + ln16;          // n
                ob[(long)row * 256 + col] = f2b(acc[r][c][e]);
            }
}

// ---------------------------------------------------------------------------
// PREFIX: in-place exclusive prefix over j: Ct[z][i] <- sum_{j<i} Ct[z][j]
// (fp32 accumulate, bf16 store).  grid (16 z, 64 dg); thread owns (d, n0..n0+7).
__global__ __launch_bounds__(256) void prefix_k(unsigned short* __restrict__ Ct) {
    int z = blockIdx.x, dg = blockIdx.y;
    int d = dg * 8 + (threadIdx.x >> 5);
    int n0 = (threadIdx.x & 31) * 8;
    long base = ((long)z * 16) * 512 * 256 + (long)d * 256 + n0;
    float acc[8] = {};
    for (int i = 0; i < 16; ++i) {
        long off = base + (long)i * 512 * 256;
        us8 cur = *(const us8*)&Ct[off];
        us8 o;
        #pragma unroll
        for (int e = 0; e < 8; ++e) o[e] = f2b(acc[e]);
        *(us8*)&Ct[off] = o;
        #pragma unroll
        for (int e = 0; e < 8; ++e) acc[e] += b2f(cur[e]);
    }
}

// ---------------------------------------------------------------------------
// SDIAG: Sd[z][i] = strict_tril(QR_i @ QR_i^T), 128x128, K=NL.  grid (16 z, 16 i).
__global__ __launch_bounds__(256) void sdiag(const unsigned short* __restrict__ qr,
                                             unsigned short* __restrict__ Sd) {
    int z = blockIdx.x, i = blockIdx.y;
    const unsigned short* Ab = qr + ((long)z * T_ + i * 128) * NL_;
    __shared__ unsigned short As[128][32];
    __shared__ unsigned short Bs[128][32];
    TILE_IDS
    v4f acc[4][4] = {};
    for (int k0 = 0; k0 < NL_; k0 += 32) {
        g2l16(Ab + (long)r0 * NL_ + k0 + c0, (char*)As + (wid * 2 + 0) * 1024);
        g2l16(Ab + (long)r1 * NL_ + k0 + c1, (char*)As + (wid * 2 + 1) * 1024);
        g2l16(Ab + (long)r0 * NL_ + k0 + c0, (char*)Bs + (wid * 2 + 0) * 1024);
        g2l16(Ab + (long)r1 * NL_ + k0 + c1, (char*)Bs + (wid * 2 + 1) * 1024);
        __syncthreads();
        TILE_MFMA(As, Bs)
        __syncthreads();
    }
    unsigned short* ob = Sd + ((long)z * 16 + i) * 16384;
    #pragma unroll
    for (int r = 0; r < 4; ++r)
        #pragma unroll
        for (int c = 0; c < 4; ++c)
            #pragma unroll
            for (int e = 0; e < 4; ++e) {
                int row = wm + r * 16 + q * 4 + e;
                int col = wn + c * 16 + ln16;
                float v = acc[r][c][e];
                if (row <= col) v = 0.f;   // strict causal
                ob[row * 128 + col] = f2b(v);
            }
}

// ---------------------------------------------------------------------------
// PXLIN: yKV = LN( QR_i @ P_i  +  Sd_i @ X_i ).  One block = 64-row strip x
// full D=512.  Uniform K=384 (12 rounds of 32): rounds 0-7 segment-1
// (A=QR strip, B=Pt tile [d][n]); rounds 8-11 segment-2 (A=Sd strip,
// B=xsT).  LN fused (block owns complete rows).  grid (16 z, 32 strip).
__global__ __launch_bounds__(256) void pxlin(
    const unsigned short* __restrict__ qr,    // [z][T][NL]
    const unsigned short* __restrict__ Pt,    // [z*16+i][512][256] (prefix)
    const unsigned short* __restrict__ Sd,    // [z*16+i][128][128]
    const unsigned short* __restrict__ xsT,   // [B][D][T]
    unsigned short* __restrict__ ykv) {       // [NH][BT][D]
    int z = blockIdx.x;
    int my = blockIdx.y;               // 64-row strip 0..31
    int i = my >> 1;                   // 128-tile
    int b = z >> 3, h = z & 7;
    const unsigned short* A1 = qr + ((long)z * T_ + my * 64) * NL_;
    const unsigned short* B1 = Pt + ((long)z * 16 + i) * 512 * 256;
    const unsigned short* A2 = Sd + ((long)z * 16 + i) * 16384 +
                               (long)(my & 1) * 64 * 128;
    const unsigned short* B2 = xsT + (long)b * D_ * T_ + i * 128;
    __shared__ unsigned short As[64][32];    //  4 KB
    __shared__ unsigned short Bs[512][32];   // 32 KB
    int tid = threadIdx.x;
    int lane = tid & 63, wid = tid >> 6;
    int ln16 = lane & 15, q = lane >> 4;
    int srl = lane >> 2, scl = (lane & 3) * 8;
    v4f yacc[4][8] = {};
    for (int r = 0; r < 12; ++r) {
        if (r < 8) {
            int k0 = r * 32;
            g2l16(A1 + (long)(wid * 16 + srl) * NL_ + k0 + scl,
                  (char*)As + wid * 1024);
            #pragma unroll
            for (int ii = 0; ii < 8; ++ii) {
                int c = wid * 8 + ii;
                g2l16(B1 + (long)(c * 16 + srl) * 256 + k0 + scl,
                      (char*)Bs + c * 1024);
            }
        } else {
            int k0 = (r - 8) * 32;
            g2l16(A2 + (long)(wid * 16 + srl) * 128 + k0 + scl,
                  (char*)As + wid * 1024);
            #pragma unroll
            for (int ii = 0; ii < 8; ++ii) {
                int c = wid * 8 + ii;
                g2l16(B2 + (long)(c * 16 + srl) * T_ + k0 + scl,
                      (char*)Bs + c * 1024);
            }
        }
        __syncthreads();
        v8bf af[4], xf[8];
        #pragma unroll
        for (int m = 0; m < 4; ++m)
            af[m] = *(const v8bf*)&As[m * 16 + ln16][q * 8];
        #pragma unroll
        for (int n = 0; n < 8; ++n)
            xf[n] = *(const v8bf*)&Bs[wid * 128 + n * 16 + ln16][q * 8];
        #pragma unroll
        for (int m = 0; m < 4; ++m)
            #pragma unroll
            for (int n = 0; n < 8; ++n)
                yacc[m][n] = __builtin_amdgcn_mfma_f32_16x16x32_bf16(
                    af[m], xf[n], yacc[m][n], 0, 0, 0);
        __syncthreads();
    }

    // ---- fused LayerNorm (two-pass, centered) over 512-wide rows ----
    __shared__ float red[64 * 4];
    float mu[4][4], inv[4][4];
    #pragma unroll
    for (int m = 0; m < 4; ++m)
        #pragma unroll
        for (int e = 0; e < 4; ++e) {
            float pr = 0.f;
            #pragma unroll
            for (int n = 0; n < 8; ++n) pr += yacc[m][n][e];
            #pragma unroll
            for (int off = 1; off < 16; off <<= 1) pr += __shfl_xor(pr, off, 64);
            if (ln16 == 0) red[(m * 16 + q * 4 + e) * 4 + wid] = pr;
        }
    __syncthreads();
    #pragma unroll
    for (int m = 0; m < 4; ++m)
        #pragma unroll
        for (int e = 0; e < 4; ++e) {
            int rl = (m * 16 + q * 4 + e) * 4;
            mu[m][e] = (red[rl] + red[rl + 1] + red[rl + 2] + red[rl + 3]) *
                       (1.0f / 512.0f);
        }
    __syncthreads();
    #pragma unroll
    for (int m = 0; m < 4; ++m)
        #pragma unroll
        for (int e = 0; e < 4; ++e) {
            float pr = 0.f;
            #pragma unroll
            for (int n = 0; n < 8; ++n) {
                float d = yacc[m][n][e] - mu[m][e];
                pr += d * d;
            }
            #pragma unroll
            for (int off = 1; off < 16; off <<= 1) pr += __shfl_xor(pr, off, 64);
            if (ln16 == 0) red[(m * 16 + q * 4 + e) * 4 + wid] = pr;
        }
    __syncthreads();
    #pragma unroll
    for (int m = 0; m < 4; ++m)
        #pragma unroll
        for (int e = 0; e < 4; ++e) {
            int rl = (m * 16 + q * 4 + e) * 4;
            float var = (red[rl] + red[rl + 1] + red[rl + 2] + red[rl + 3]) *
                        (1.0f / 512.0f);
            inv[m][e] = rsqrtf(var + 1e-5f);
        }
    #pragma unroll
    for (int m = 0; m < 4; ++m)
        #pragma unroll
        for (int n = 0; n < 8; ++n)
            #pragma unroll
            for (int e = 0; e < 4; ++e) {
                int t = my * 64 + m * 16 + q * 4 + e;
                int d = wid * 128 + n * 16 + ln16;
                float vv = (yacc[m][n][e] - mu[m][e]) * inv[m][e];
                ykv[((long)h * BT_ + (long)b * T_ + t) * D_ + d] = f2b(vv);
            }
}

// ---------------------------------------------------------------------------
// Transpose + cast fp32 -> bf16: out[Cc][R] = (bf16) in[R][Cc], batched.
__global__ __launch_bounds__(256) void trans_cast(
    const float* __restrict__ in, long sIn, unsigned short* __restrict__ out,
    long sOut, int R, int Cc) {
    __shared__ float tl[32][33];
    int z = blockIdx.z;
    int r0 = blockIdx.y * 32, c0 = blockIdx.x * 32;
    int tx = threadIdx.x & 31, ty = threadIdx.x >> 5;
    const float* ip = in + (long)z * sIn;
    unsigned short* op = out + (long)z * sOut;
    #pragma unroll
    for (int j = 0; j < 4; ++j)
        tl[ty + j * 8][tx] = ip[(long)(r0 + ty + j * 8) * Cc + c0 + tx];
    __syncthreads();
    #pragma unroll
    for (int j = 0; j < 4; ++j)
        op[(long)(c0 + ty + j * 8) * R + r0 + tx] = f2b(tl[tx][ty + j * 8]);
}

// bf16 transpose: out[Cc][R] = in[R][Cc], batched.
__global__ __launch_bounds__(256) void trans_b16(
    const unsigned short* __restrict__ in, long sIn,
    unsigned short* __restrict__ out, long sOut, int R, int Cc) {
    __shared__ unsigned short tl[32][33];
    int z = blockIdx.z;
    int r0 = blockIdx.y * 32, c0 = blockIdx.x * 32;
    int tx = threadIdx.x & 31, ty = threadIdx.x >> 5;
    const unsigned short* ip = in + (long)z * sIn;
    unsigned short* op = out + (long)z * sOut;
    #pragma unroll
    for (int j = 0; j < 4; ++j)
        tl[ty + j * 8][tx] = ip[(long)(r0 + ty + j * 8) * Cc + c0 + tx];
    __syncthreads();
    #pragma unroll
    for (int j = 0; j < 4; ++j)
        op[(long)(c0 + ty + j * 8) * R + r0 + tx] = tl[tx][ty + j * 8];
}

// fp32 -> bf16 elementwise (n multiple of 1024)
__global__ __launch_bounds__(256) void cast_b(const float* __restrict__ in,
                                              unsigned short* __restrict__ out) {
    long i = ((long)blockIdx.x * 256 + threadIdx.x) * 4;
    float4 v = *(const float4*)&in[i];
    ushort4 o;
    o.x = f2b(v.x); o.y = f2b(v.y); o.z = f2b(v.z); o.w = f2b(v.w);
    *(ushort4*)&out[i] = o;
}

// out = t0+t1+t2+t3 + bias (4 split-K slices, rows of 512)
__global__ __launch_bounds__(256) void add_out4(const float* __restrict__ t,
                                                long slice,
                                                const float* __restrict__ bias,
                                                float* __restrict__ o) {
    long i = ((long)blockIdx.x * 256 + threadIdx.x) * 4;
    float4 v0 = *(const float4*)&t[i];
    float4 v1 = *(const float4*)&t[i + slice];
    float4 v2 = *(const float4*)&t[i + 2 * slice];
    float4 v3 = *(const float4*)&t[i + 3 * slice];
    float4 bv = *(const float4*)&bias[i & 511];
    float4 r;
    r.x = v0.x + v1.x + v2.x + v3.x + bv.x;
    r.y = v0.y + v1.y + v2.y + v3.y + bv.y;
    r.z = v0.z + v1.z + v2.z + v3.z + bv.z;
    r.w = v0.w + v1.w + v2.w + v3.w + bv.w;
    *(float4*)&o[i] = r;
}

// ---------------------------------------------------------------------------
// RoPE: xsp [BT][HN] bf16 -> qr [B][NH][T][NL] bf16 (head-outer layout).
__global__ __launch_bounds__(256) void rope_b(const unsigned short* __restrict__ xsp,
                                              unsigned short* __restrict__ qr) {
    long i = (long)blockIdx.x * 256 + threadIdx.x;  // group of 4 pairs
    int g = (int)(i & 255);
    long row = i >> 8;
    int h = g >> 5, n8 = g & 31;
    long b = row >> 11;
    int t = (int)(row & (T_ - 1));
    us8 u = *(const us8*)&xsp[row * HN_ + (long)g * 8];
    us8 o;
    #pragma unroll
    for (int p = 0; p < 4; ++p) {
        int n2 = n8 * 4 + p;
        float f = exp2f(-(float)n2 * 0.125f) * (float)(1.0 / (2.0 * M_PI));
        float ph = (float)t * f;
        ph = (ph - floorf(ph)) * (float)(2.0 * M_PI);
        float s, c;
        __sincosf(ph, &s, &c);
        float x0 = b2f(u[2 * p]), x1 = b2f(u[2 * p + 1]);
        o[2 * p]     = f2b(x0 * c - x1 * s);
        o[2 * p + 1] = f2b(x1 * c + x0 * s);
    }
    long ob = (((b * NH_ + h) * T_ + t) * NL_) + (long)n8 * 8;
    *(us8*)&qr[ob] = o;
}

// ---------------------------------------------------------------------------
// LayerNorm helpers (rows of 512, 256 threads, float2 per thread)
__device__ inline float2 block_reduce2(float a, float b) {
    __shared__ float sa[4], sb[4];
    #pragma unroll
    for (int off = 32; off; off >>= 1) {
        a += __shfl_down(a, off, 64);
        b += __shfl_down(b, off, 64);
    }
    __syncthreads();
    int w = threadIdx.x >> 6;
    if ((threadIdx.x & 63) == 0) { sa[w] = a; sb[w] = b; }
    __syncthreads();
    return make_float2(sa[0] + sa[1] + sa[2] + sa[3],
                       sb[0] + sb[1] + sb[2] + sb[3]);
}
__device__ inline float2 ln_pair(float2 v) {
    float2 s = block_reduce2(v.x + v.y, 0.f);
    float mu = s.x * (1.0f / 512.0f);
    float dx = v.x - mu, dy = v.y - mu;
    float2 q = block_reduce2(dx * dx + dy * dy, 0.f);
    float inv = rsqrtf(q.x * (1.0f / 512.0f) + 1e-5f);
    return make_float2(dx * inv, dy * inv);
}

// LN(sum of 4 slices + bias) -> fp32 + bf16
__global__ __launch_bounds__(256) void ln_dual4(const float* __restrict__ t,
                                                long slice,
                                                const float* __restrict__ bias,
                                                float* __restrict__ outf,
                                                unsigned short* __restrict__ outb) {
    long row = blockIdx.x;
    int c = threadIdx.x * 2;
    long i = row * 512 + c;
    float2 v0 = *(const float2*)&t[i];
    float2 v1 = *(const float2*)&t[i + slice];
    float2 v2 = *(const float2*)&t[i + 2 * slice];
    float2 v3 = *(const float2*)&t[i + 3 * slice];
    float2 bv = *(const float2*)&bias[c];
    float2 v = make_float2(v0.x + v1.x + v2.x + v3.x + bv.x,
                           v0.y + v1.y + v2.y + v3.y + bv.y);
    float2 o = ln_pair(v);
    *(float2*)&outf[i] = o;
    ushort2 ob; ob.x = f2b(o.x); ob.y = f2b(o.y);
    *(ushort2*)&outb[i] = ob;
}

// xs_next = LN(x_res + LN(sum of 4 ymlp slices)) -> fp32 + bf16
__global__ __launch_bounds__(256) void combine_dual4(
    const float* __restrict__ t, long slice, const float* __restrict__ xres,
    float* __restrict__ outf, unsigned short* __restrict__ outb) {
    long row = blockIdx.x;
    int c = threadIdx.x * 2;
    long i = row * 512 + c;
    float2 v0 = *(const float2*)&t[i];
    float2 v1 = *(const float2*)&t[i + slice];
    float2 v2 = *(const float2*)&t[i + 2 * slice];
    float2 v3 = *(const float2*)&t[i + 3 * slice];
    float2 y = make_float2(v0.x + v1.x + v2.x + v3.x,
                           v0.y + v1.y + v2.y + v3.y);
    float2 l = ln_pair(y);
    float2 r = *(const float2*)&xres[i];
    float2 z = make_float2(r.x + l.x, r.y + l.y);
    float2 o = ln_pair(z);
    *(float2*)&outf[i] = o;
    ushort2 ob; ob.x = f2b(o.x); ob.y = f2b(o.y);
    *(ushort2*)&outb[i] = ob;
}

// ---------------------------------------------------------------------------
extern "C" void kernel_launch(void* const* d_in, const int* in_sizes, int n_in,
                              void* d_out, int out_size, void* d_ws,
                              size_t ws_size, hipStream_t stream) {
    const float* x      = (const float*)d_in[0];
    const float* w_in   = (const float*)d_in[1];
    const float* b_in   = (const float*)d_in[2];
    const float* enc    = (const float*)d_in[3];
    const float* enc_v  = (const float*)d_in[4];
    const float* dec    = (const float*)d_in[5];
    const float* head_w = (const float*)d_in[6];
    const float* head_b = (const float*)d_in[7];
    float* out = (float*)d_out;

    // ---- workspace (~215 MB) ----
    char* w = (char*)d_ws;
    auto alloc = [&](size_t bytes) { void* p = (void*)w; w += bytes; return p; };
    unsigned short* w_inT = (unsigned short*)alloc((size_t)512 * 512 * 2);
    unsigned short* headT = (unsigned short*)alloc((size_t)512 * 512 * 2);
    unsigned short* encT  = (unsigned short*)alloc((size_t)NH_ * NL_ * D_ * 2);
    unsigned short* encvT = (unsigned short*)alloc((size_t)NH_ * NL_ * D_ * 2);
    unsigned short* decT  = (unsigned short*)alloc((size_t)D_ * HN_ * 2);
    unsigned short* xb    = (unsigned short*)alloc((size_t)BT_ * D_ * 2);
    float*          tmp   = (float*)alloc((size_t)4 * BT_ * D_ * 4);  // 4 K-slices
    float*          xsf0  = (float*)alloc((size_t)BT_ * D_ * 4);
    float*          xsf1  = (float*)alloc((size_t)BT_ * D_ * 4);
    unsigned short* xs_b  = (unsigned short*)alloc((size_t)BT_ * D_ * 2);
    unsigned short* xsT   = (unsigned short*)alloc((size_t)B_ * D_ * T_ * 2);
    unsigned short* xsp   = (unsigned short*)alloc((size_t)BT_ * HN_ * 2);
    unsigned short* qrh   = (unsigned short*)alloc((size_t)BT_ * HN_ * 2);
    unsigned short* qrT   = (unsigned short*)alloc((size_t)BT_ * HN_ * 2);
    unsigned short* Ct    = (unsigned short*)alloc((size_t)256 * 512 * 256 * 2); // 67 MB
    unsigned short* Sd    = (unsigned short*)alloc((size_t)256 * 128 * 128 * 2); //  8 MB
    unsigned short* ykv   = (unsigned short*)alloc((size_t)NH_ * BT_ * D_ * 2);
    const long SL = (long)BT_ * D_;   // split-K slice stride (elements)

    // ---- prep ----
    cast_b<<<BT_ * D_ / 1024, 256, 0, stream>>>(x, xb);
    trans_cast<<<dim3(16, 16, 1), 256, 0, stream>>>(w_in, 0, w_inT, 0, 512, 512);
    trans_cast<<<dim3(16, 16, 1), 256, 0, stream>>>(head_w, 0, headT, 0, 512, 512);
    trans_cast<<<dim3(8, 16, 8), 256, 0, stream>>>(enc, (long)D_ * NL_, encT,
                                                   (long)NL_ * D_, D_, NL_);
    trans_cast<<<dim3(8, 16, 8), 256, 0, stream>>>(enc_v, (long)D_ * NL_, encvT,
                                                   (long)NL_ * D_, D_, NL_);
    trans_cast<<<dim3(16, 64, 1), 256, 0, stream>>>(dec, 0, decT, 0, HN_, D_);

    // ---- xs = LN(x @ w_in + b_in)  (split-K=4) ----
    gemm64<false, false, false>
        <<<dim3(4, 64, 4), 256, 0, stream>>>(xb, D_, 128, w_inT, D_, 128, tmp,
                                             D_, SL, nullptr, BT_, D_, 128);
    ln_dual4<<<BT_, 256, 0, stream>>>(tmp, SL, b_in, xsf0, xs_b);
    trans_cast<<<dim3(16, 64, 2), 256, 0, stream>>>(xsf0, (long)T_ * D_, xsT,
                                                    (long)D_ * T_, T_, D_);

    float* xin = xsf0;
    float* xout = xsf1;
    for (int l = 0; l < 3; ++l) {
        // x_sparse = relu(xs @ enc) -> bf16 [BT][HN]
        gemm64<true, false, true>
            <<<dim3(16, 64, 1), 256, 0, stream>>>(
                xs_b, D_, 0, encT, D_, 0, xsp, HN_, 0, nullptr, BT_, HN_, D_);
        // QR = rope(x_sparse) -> [B][NH][T][NL], and QR^T -> [z][NL][T]
        rope_b<<<BT_ * HN_ / 8 / 256, 256, 0, stream>>>(xsp, qrh);
        trans_b16<<<dim3(8, 64, 16), 256, 0, stream>>>(
            qrh, (long)T_ * NL_, qrT, (long)NL_ * T_, T_, NL_);
        // linear-attention state tiles: Ct[z][j] = X_j^T @ QR_j
        ct_gemm<<<dim3(16, 2, 128), 256, 0, stream>>>(xsT, qrT, Ct);
        // exclusive prefix over j (in place)
        prefix_k<<<dim3(16, 64), 256, 0, stream>>>(Ct);
        // diagonal strict scores
        sdiag<<<dim3(16, 16), 256, 0, stream>>>(qrh, Sd);
        // yKV = LN( QR_i @ P_i + Sd_i @ X_i )
        pxlin<<<dim3(16, 32), 256, 0, stream>>>(qrh, Ct, Sd, xsT, ykv);
        // xy = relu(yKV[h] @ enc_v[h]) * x_sparse — per-head batched
        gemm64<true, true, true>
            <<<dim3(2, 64, 8), 256, 0, stream>>>(
                ykv, D_, (long)BT_ * D_, encvT, D_, (long)NL_ * D_, xsp, HN_,
                NL_, xsp, BT_, NL_, D_);
        // yMLP = xy @ decoder  (split-K=4) -> fp32 slices
        gemm64<false, false, false>
            <<<dim3(4, 64, 4), 256, 0, stream>>>(
                xsp, HN_, 512, decT, HN_, 512, tmp, D_, SL, nullptr, BT_, D_,
                512);
        // xs = LN(x_res + LN(yMLP))
        combine_dual4<<<BT_, 256, 0, stream>>>(tmp, SL, xin, xout, xs_b);
        trans_cast<<<dim3(16, 64, 2), 256, 0, stream>>>(xout, (long)T_ * D_,
                                                        xsT, (long)D_ * T_, T_,
                                                        D_);
        float* t = xin; xin = xout; xout = t;
    }

    // logits = xs @ head_w + head_b  (split-K=4)
    gemm64<false, false, false>
        <<<dim3(4, 64, 4), 256, 0, stream>>>(xs_b, D_, 128, headT, D_, 128, tmp,
                                             D_, SL, nullptr, BT_, D_, 128);
    add_out4<<<BT_ * 512 / 1024, 256, 0, stream>>>(tmp, SL, head_b, out);
}

// Round 13
// 695.899 us; speedup vs baseline: 1.1966x; 1.0210x over previous
//
#include <hip/hip_runtime.h>
#include <math.h>

constexpr int B_  = 2;
constexpr int T_  = 2048;
constexpr int D_  = 512;
constexpr int NH_ = 8;
constexpr int NL_ = 256;
constexpr int HN_ = NH_ * NL_;   // 2048
constexpr int BT_ = B_ * T_;     // 4096

typedef __bf16 v8bf __attribute__((ext_vector_type(8)));
typedef float  v4f  __attribute__((ext_vector_type(4)));
typedef unsigned short us8 __attribute__((ext_vector_type(8)));
typedef unsigned short us4 __attribute__((ext_vector_type(4)));

__device__ inline unsigned short f2b(float f) {
    union { float f; unsigned u; } v{f};
    unsigned r = v.u + 0x7FFF + ((v.u >> 16) & 1);   // rtne
    return (unsigned short)(r >> 16);
}
__device__ inline float b2f(unsigned short u) {
    union { unsigned u; float f; } v{(unsigned)u << 16};
    return v.f;
}

// async 16B global->LDS (per-lane gaddr; LDS dest = wave-uniform base + lane*16)
__device__ __forceinline__ void g2l16(const void* g, void* l) {
    __builtin_amdgcn_global_load_lds(
        (const __attribute__((address_space(1))) void*)g,
        (__attribute__((address_space(3))) void*)l, 16, 0, 0);
}

// ===========================================================================
// 128x128-tile core: 4 waves 2x2, 4x4 MFMA/wave.
#define TILE_IDS                                              \
    int tid = threadIdx.x;                                    \
    int lane = tid & 63, wid = tid >> 6;                      \
    int wm = (wid & 1) * 64, wn = (wid >> 1) * 64;            \
    int ln16 = lane & 15, q = lane >> 4;                      \
    int e0 = (wid * 2 + 0) * 512 + lane * 8;                  \
    int e1 = (wid * 2 + 1) * 512 + lane * 8;                  \
    int r0 = e0 >> 5, c0 = e0 & 31, r1 = e1 >> 5, c1 = e1 & 31;

#define TILE_MFMA(As, Bs)                                     \
    {                                                         \
        v8bf af[4], bfr[4];                                   \
        _Pragma("unroll")                                     \
        for (int r = 0; r < 4; ++r)                           \
            af[r] = *(const v8bf*)&As[wm + r * 16 + ln16][q * 8]; \
        _Pragma("unroll")                                     \
        for (int c = 0; c < 4; ++c)                           \
            bfr[c] = *(const v8bf*)&Bs[wn + c * 16 + ln16][q * 8]; \
        _Pragma("unroll")                                     \
        for (int r = 0; r < 4; ++r)                           \
            _Pragma("unroll")                                 \
            for (int c = 0; c < 4; ++c)                       \
                acc[r][c] = __builtin_amdgcn_mfma_f32_16x16x32_bf16( \
                    af[r], bfr[c], acc[r][c], 0, 0, 0);       \
    }

// ===========================================================================
// 64x128-tile core: 4 waves n-split 32, 4x2 MFMA.
#define T64_IDS                                               \
    int tid = threadIdx.x;                                    \
    int lane = tid & 63, wid = tid >> 6;                      \
    int wn = wid * 32;                                        \
    int ln16 = lane & 15, q = lane >> 4;                      \
    int srl = lane >> 2, scl = (lane & 3) * 8;

#define T64_STAGE(Ab, lda, Bb, ldb, k0)                       \
    _Pragma("unroll")                                         \
    for (int ci = 0; ci < 3; ++ci) {                          \
        int c = wid * 3 + ci;                                 \
        if (c < 4) {                                          \
            int r = c * 16 + srl;                             \
            g2l16(Ab + (long)r * lda + (k0) + scl, (char*)As + c * 1024); \
        } else {                                              \
            int r = (c - 4) * 16 + srl;                       \
            g2l16(Bb + (long)r * ldb + (k0) + scl, (char*)Bs + (c - 4) * 1024); \
        }                                                     \
    }

#define T64_MFMA(As, Bs)                                      \
    {                                                         \
        v8bf af[4], bf2[2];                                   \
        _Pragma("unroll")                                     \
        for (int r = 0; r < 4; ++r)                           \
            af[r] = *(const v8bf*)&As[r * 16 + ln16][q * 8];  \
        _Pragma("unroll")                                     \
        for (int c = 0; c < 2; ++c)                           \
            bf2[c] = *(const v8bf*)&Bs[wn + c * 16 + ln16][q * 8]; \
        _Pragma("unroll")                                     \
        for (int r = 0; r < 4; ++r)                           \
            _Pragma("unroll")                                 \
            for (int c = 0; c < 2; ++c)                       \
                acc[r][c] = __builtin_amdgcn_mfma_f32_16x16x32_bf16( \
                    af[r], bf2[c], acc[r][c], 0, 0, 0);       \
    }

// ---------------------------------------------------------------------------
// Generic 64-row bf16 GEMM: C[M,N] = A[M,K] @ Bt[N,K]^T, z-batched.
template <bool RELU, bool MUL, bool BF16OUT>
__global__ __launch_bounds__(256) void gemm64(
    const unsigned short* __restrict__ A, int lda, long sA,
    const unsigned short* __restrict__ Bt, int ldb, long sB,
    void* __restrict__ Cv, int ldc, long sC,
    const unsigned short* __restrict__ mulp, int M, int N, int K) {
    int m0 = blockIdx.y * 64, n0 = blockIdx.x * 128, z = blockIdx.z;
    __shared__ unsigned short As[64][32];    // 4 KB
    __shared__ unsigned short Bs[128][32];   // 8 KB
    const unsigned short* Ab = A  + (long)z * sA + (long)m0 * lda;
    const unsigned short* Bb = Bt + (long)z * sB + (long)n0 * ldb;
    T64_IDS
    v4f acc[4][2] = {};
    for (int k0 = 0; k0 < K; k0 += 32) {
        T64_STAGE(Ab, lda, Bb, ldb, k0)
        __syncthreads();
        T64_MFMA(As, Bs)
        __syncthreads();
    }
    float* Cf = (float*)Cv;
    unsigned short* Cb = (unsigned short*)Cv;
    long zoff = (long)z * sC;
    #pragma unroll
    for (int r = 0; r < 4; ++r)
        #pragma unroll
        for (int c = 0; c < 2; ++c)
            #pragma unroll
            for (int e = 0; e < 4; ++e) {
                int row = m0 + r * 16 + q * 4 + e;
                int col = n0 + wn + c * 16 + ln16;
                float v = acc[r][c][e];
                if (RELU) v = fmaxf(v, 0.f);
                long idx = zoff + (long)row * ldc + col;
                if (MUL) v *= b2f(mulp[idx]);
                if (BF16OUT) Cb[idx] = f2b(v);
                else         Cf[idx] = v;
            }
}

// ---------------------------------------------------------------------------
// ENC+ROPE fused: x_sparse = relu(xs @ enc) -> xsp [BT][HN]; QR = rope(xsp)
// -> qrh [z][T][NL] AND qrT [z][NL][T] (via LDS transpose).  Pair partner of
// column n is held by lane^1 (cols map to ln16): one shfl_xor.
// grid (16 n-tiles, 64 row-tiles).
__global__ __launch_bounds__(256) void enc_rope(
    const unsigned short* __restrict__ A,    // xs_b [BT][512]
    const unsigned short* __restrict__ Bt,   // encT [HN][512] K-major
    unsigned short* __restrict__ xsp,        // [BT][HN]
    unsigned short* __restrict__ qrh,        // [z][T][NL]
    unsigned short* __restrict__ qrT) {      // [z][NL][T]
    int m0 = blockIdx.y * 64, n0 = blockIdx.x * 128;
    __shared__ unsigned short As[64][32];
    __shared__ unsigned short Bs[128][32];
    __shared__ unsigned short lt[128][72];   // [n-local][t-local], pad 8
    const unsigned short* Ab = A + (long)m0 * 512;
    const unsigned short* Bb = Bt + (long)n0 * 512;
    T64_IDS
    v4f acc[4][2] = {};
    for (int k0 = 0; k0 < 512; k0 += 32) {
        T64_STAGE(Ab, 512, Bb, 512, k0)
        __syncthreads();
        T64_MFMA(As, Bs)
        __syncthreads();
    }
    int bb = m0 >> 11;                  // batch
    int tbase = m0 & (T_ - 1);
    #pragma unroll
    for (int r = 0; r < 4; ++r)
        #pragma unroll
        for (int c = 0; c < 2; ++c)
            #pragma unroll
            for (int e = 0; e < 4; ++e) {
                int rl = r * 16 + q * 4 + e;
                int col = n0 + wn + c * 16 + ln16;
                float v = fmaxf(acc[r][c][e], 0.f);
                xsp[(long)(m0 + rl) * HN_ + col] = f2b(v);
                int n = col & (NL_ - 1);
                int n2 = n >> 1;
                float fr = exp2f(-(float)n2 * 0.125f) *
                           (float)(1.0 / (2.0 * M_PI));
                float ph = (float)(tbase + rl) * fr;
                ph = (ph - floorf(ph)) * (float)(2.0 * M_PI);
                float s, cc;
                __sincosf(ph, &s, &cc);
                float vp = __shfl_xor(v, 1, 64);   // partner col^1
                float o = (n & 1) ? (v * cc + vp * s) : (v * cc - vp * s);
                int hh = col >> 8;
                qrh[((long)(bb * 8 + hh) * T_ + tbase + rl) * NL_ + n] = f2b(o);
                lt[wn + c * 16 + ln16][rl] = f2b(o);
            }
    __syncthreads();
    // qrT: 128 n-rows x 64 t, 32 shorts per thread (8B chunks; row 144B)
    {
        int nrow = tid >> 1, tseg = (tid & 1) * 32;
        int colg = n0 + nrow;
        int hh = colg >> 8, nn = colg & (NL_ - 1);
        long ob = ((long)(bb * 8 + hh) * NL_ + nn) * T_ + tbase + tseg;
        #pragma unroll
        for (int u = 0; u < 8; ++u)
            *(us4*)&qrT[ob + u * 4] = *(const us4*)&lt[nrow][tseg + u * 4];
    }
}

// ---------------------------------------------------------------------------
// CT-GEMM (linear-attn state tiles): Ct[z][j][d][n] = X_j^T @ QR_j.
// grid (16 z, 2 nt, 128 = j*8+mt); z fastest -> XCD pin.
__global__ __launch_bounds__(256) void ct_gemm(
    const unsigned short* __restrict__ xsT,   // [B][D][T]
    const unsigned short* __restrict__ qrT,   // [B*NH][NL][T]
    unsigned short* __restrict__ Ct) {        // [z*16+j][512][256]
    int z = blockIdx.x, nt = blockIdx.y;
    int j = blockIdx.z >> 3, mt = blockIdx.z & 7;
    int b = z >> 3;
    const unsigned short* Ab =
        xsT + (long)b * D_ * T_ + (long)(mt * 64) * T_ + j * 128;
    const unsigned short* Bb =
        qrT + (long)z * NL_ * T_ + (long)(nt * 128) * T_ + j * 128;
    __shared__ unsigned short As[64][32];
    __shared__ unsigned short Bs[128][32];
    T64_IDS
    v4f acc[4][2] = {};
    for (int k0 = 0; k0 < 128; k0 += 32) {
        T64_STAGE(Ab, T_, Bb, T_, k0)
        __syncthreads();
        T64_MFMA(As, Bs)
        __syncthreads();
    }
    unsigned short* ob = Ct + ((long)z * 16 + j) * 512 * 256;
    #pragma unroll
    for (int r = 0; r < 4; ++r)
        #pragma unroll
        for (int c = 0; c < 2; ++c)
            #pragma unroll
            for (int e = 0; e < 4; ++e) {
                int row = mt * 64 + r * 16 + q * 4 + e;           // d
                int col = nt * 128 + wn + c * 16 + ln16;          // n
                ob[(long)row * 256 + col] = f2b(acc[r][c][e]);
            }
}

// ---------------------------------------------------------------------------
// PREFIX: in-place exclusive prefix over j: Ct[z][i] <- sum_{j<i} Ct[z][j]
// (fp32 accumulate, bf16 store).  grid (16 z, 64 dg).
__global__ __launch_bounds__(256) void prefix_k(unsigned short* __restrict__ Ct) {
    int z = blockIdx.x, dg = blockIdx.y;
    int d = dg * 8 + (threadIdx.x >> 5);
    int n0 = (threadIdx.x & 31) * 8;
    long base = ((long)z * 16) * 512 * 256 + (long)d * 256 + n0;
    float acc[8] = {};
    for (int i = 0; i < 16; ++i) {
        long off = base + (long)i * 512 * 256;
        us8 cur = *(const us8*)&Ct[off];
        us8 o;
        #pragma unroll
        for (int e = 0; e < 8; ++e) o[e] = f2b(acc[e]);
        *(us8*)&Ct[off] = o;
        #pragma unroll
        for (int e = 0; e < 8; ++e) acc[e] += b2f(cur[e]);
    }
}

// ---------------------------------------------------------------------------
// SDIAG: Sd[z][i] = strict_tril(QR_i @ QR_i^T), 128x128, K=NL.  grid (16 z, 16 i).
__global__ __launch_bounds__(256) void sdiag(const unsigned short* __restrict__ qr,
                                             unsigned short* __restrict__ Sd) {
    int z = blockIdx.x, i = blockIdx.y;
    const unsigned short* Ab = qr + ((long)z * T_ + i * 128) * NL_;
    __shared__ unsigned short As[128][32];
    __shared__ unsigned short Bs[128][32];
    TILE_IDS
    v4f acc[4][4] = {};
    for (int k0 = 0; k0 < NL_; k0 += 32) {
        g2l16(Ab + (long)r0 * NL_ + k0 + c0, (char*)As + (wid * 2 + 0) * 1024);
        g2l16(Ab + (long)r1 * NL_ + k0 + c1, (char*)As + (wid * 2 + 1) * 1024);
        g2l16(Ab + (long)r0 * NL_ + k0 + c0, (char*)Bs + (wid * 2 + 0) * 1024);
        g2l16(Ab + (long)r1 * NL_ + k0 + c1, (char*)Bs + (wid * 2 + 1) * 1024);
        __syncthreads();
        TILE_MFMA(As, Bs)
        __syncthreads();
    }
    unsigned short* ob = Sd + ((long)z * 16 + i) * 16384;
    #pragma unroll
    for (int r = 0; r < 4; ++r)
        #pragma unroll
        for (int c = 0; c < 4; ++c)
            #pragma unroll
            for (int e = 0; e < 4; ++e) {
                int row = wm + r * 16 + q * 4 + e;
                int col = wn + c * 16 + ln16;
                float v = acc[r][c][e];
                if (row <= col) v = 0.f;   // strict causal
                ob[row * 128 + col] = f2b(v);
            }
}

// ---------------------------------------------------------------------------
// PXLIN v2: yKV = LN( QR_i @ P_i + Sd_i @ X_i ).  BK=64 (two 32-halves staged
// per round): 6 rounds total (4 seg-1 + 2 seg-2), 64 MFMA/wave between
// barriers.  LDS 72 KB -> 2 blocks/CU.  grid (16 z, 32 strip).
__global__ __launch_bounds__(256) void pxlin(
    const unsigned short* __restrict__ qr,    // [z][T][NL]
    const unsigned short* __restrict__ Pt,    // [z*16+i][512][256] (prefix)
    const unsigned short* __restrict__ Sd,    // [z*16+i][128][128]
    const unsigned short* __restrict__ xsT,   // [B][D][T]
    unsigned short* __restrict__ ykv) {       // [NH][BT][D]
    int z = blockIdx.x;
    int my = blockIdx.y;               // 64-row strip 0..31
    int i = my >> 1;                   // 128-tile
    int b = z >> 3, h = z & 7;
    const unsigned short* A1 = qr + ((long)z * T_ + my * 64) * NL_;
    const unsigned short* B1 = Pt + ((long)z * 16 + i) * 512 * 256;
    const unsigned short* A2 = Sd + ((long)z * 16 + i) * 16384 +
                               (long)(my & 1) * 64 * 128;
    const unsigned short* B2 = xsT + (long)b * D_ * T_ + i * 128;
    __shared__ unsigned short As[2][64 * 32];    //  8 KB
    __shared__ unsigned short Bs[2][512 * 32];   // 64 KB
    int tid = threadIdx.x;
    int lane = tid & 63, wid = tid >> 6;
    int ln16 = lane & 15, q = lane >> 4;
    int srl = lane >> 2, scl = (lane & 3) * 8;
    v4f yacc[4][8] = {};
    for (int r = 0; r < 6; ++r) {
        const unsigned short* Ap;
        const unsigned short* Bp;
        long lda, ldb;
        int k0;
        if (r < 4) { Ap = A1; lda = NL_; Bp = B1; ldb = 256; k0 = r * 64; }
        else       { Ap = A2; lda = 128; Bp = B2; ldb = T_;  k0 = (r - 4) * 64; }
        #pragma unroll
        for (int hf = 0; hf < 2; ++hf) {
            g2l16(Ap + (long)(wid * 16 + srl) * lda + k0 + hf * 32 + scl,
                  (char*)&As[hf][0] + wid * 1024);
            #pragma unroll
            for (int ii = 0; ii < 8; ++ii) {
                int c = wid * 8 + ii;
                g2l16(Bp + (long)(c * 16 + srl) * ldb + k0 + hf * 32 + scl,
                      (char*)&Bs[hf][0] + c * 1024);
            }
        }
        __syncthreads();
        #pragma unroll
        for (int hf = 0; hf < 2; ++hf) {
            v8bf af[4], xf[8];
            #pragma unroll
            for (int m = 0; m < 4; ++m)
                af[m] = *(const v8bf*)&As[hf][(m * 16 + ln16) * 32 + q * 8];
            #pragma unroll
            for (int n = 0; n < 8; ++n)
                xf[n] = *(const v8bf*)
                    &Bs[hf][(wid * 128 + n * 16 + ln16) * 32 + q * 8];
            #pragma unroll
            for (int m = 0; m < 4; ++m)
                #pragma unroll
                for (int n = 0; n < 8; ++n)
                    yacc[m][n] = __builtin_amdgcn_mfma_f32_16x16x32_bf16(
                        af[m], xf[n], yacc[m][n], 0, 0, 0);
        }
        __syncthreads();
    }

    // ---- fused LayerNorm (two-pass, centered) over 512-wide rows ----
    __shared__ float red[64 * 4];
    float mu[4][4], inv[4][4];
    #pragma unroll
    for (int m = 0; m < 4; ++m)
        #pragma unroll
        for (int e = 0; e < 4; ++e) {
            float pr = 0.f;
            #pragma unroll
            for (int n = 0; n < 8; ++n) pr += yacc[m][n][e];
            #pragma unroll
            for (int off = 1; off < 16; off <<= 1) pr += __shfl_xor(pr, off, 64);
            if (ln16 == 0) red[(m * 16 + q * 4 + e) * 4 + wid] = pr;
        }
    __syncthreads();
    #pragma unroll
    for (int m = 0; m < 4; ++m)
        #pragma unroll
        for (int e = 0; e < 4; ++e) {
            int rl = (m * 16 + q * 4 + e) * 4;
            mu[m][e] = (red[rl] + red[rl + 1] + red[rl + 2] + red[rl + 3]) *
                       (1.0f / 512.0f);
        }
    __syncthreads();
    #pragma unroll
    for (int m = 0; m < 4; ++m)
        #pragma unroll
        for (int e = 0; e < 4; ++e) {
            float pr = 0.f;
            #pragma unroll
            for (int n = 0; n < 8; ++n) {
                float d = yacc[m][n][e] - mu[m][e];
                pr += d * d;
            }
            #pragma unroll
            for (int off = 1; off < 16; off <<= 1) pr += __shfl_xor(pr, off, 64);
            if (ln16 == 0) red[(m * 16 + q * 4 + e) * 4 + wid] = pr;
        }
    __syncthreads();
    #pragma unroll
    for (int m = 0; m < 4; ++m)
        #pragma unroll
        for (int e = 0; e < 4; ++e) {
            int rl = (m * 16 + q * 4 + e) * 4;
            float var = (red[rl] + red[rl + 1] + red[rl + 2] + red[rl + 3]) *
                        (1.0f / 512.0f);
            inv[m][e] = rsqrtf(var + 1e-5f);
        }
    #pragma unroll
    for (int m = 0; m < 4; ++m)
        #pragma unroll
        for (int n = 0; n < 8; ++n)
            #pragma unroll
            for (int e = 0; e < 4; ++e) {
                int t = my * 64 + m * 16 + q * 4 + e;
                int d = wid * 128 + n * 16 + ln16;
                float vv = (yacc[m][n][e] - mu[m][e]) * inv[m][e];
                ykv[((long)h * BT_ + (long)b * T_ + t) * D_ + d] = f2b(vv);
            }
}

// ---------------------------------------------------------------------------
// Transpose + cast fp32 -> bf16: out[Cc][R] = (bf16) in[R][Cc], batched.
__global__ __launch_bounds__(256) void trans_cast(
    const float* __restrict__ in, long sIn, unsigned short* __restrict__ out,
    long sOut, int R, int Cc) {
    __shared__ float tl[32][33];
    int z = blockIdx.z;
    int r0 = blockIdx.y * 32, c0 = blockIdx.x * 32;
    int tx = threadIdx.x & 31, ty = threadIdx.x >> 5;
    const float* ip = in + (long)z * sIn;
    unsigned short* op = out + (long)z * sOut;
    #pragma unroll
    for (int j = 0; j < 4; ++j)
        tl[ty + j * 8][tx] = ip[(long)(r0 + ty + j * 8) * Cc + c0 + tx];
    __syncthreads();
    #pragma unroll
    for (int j = 0; j < 4; ++j)
        op[(long)(c0 + ty + j * 8) * R + r0 + tx] = f2b(tl[tx][ty + j * 8]);
}

// fp32 -> bf16 elementwise (n multiple of 1024)
__global__ __launch_bounds__(256) void cast_b(const float* __restrict__ in,
                                              unsigned short* __restrict__ out) {
    long i = ((long)blockIdx.x * 256 + threadIdx.x) * 4;
    float4 v = *(const float4*)&in[i];
    ushort4 o;
    o.x = f2b(v.x); o.y = f2b(v.y); o.z = f2b(v.z); o.w = f2b(v.w);
    *(ushort4*)&out[i] = o;
}

// out = t0+t1+t2+t3 + bias (4 split-K slices, rows of 512)
__global__ __launch_bounds__(256) void add_out4(const float* __restrict__ t,
                                                long slice,
                                                const float* __restrict__ bias,
                                                float* __restrict__ o) {
    long i = ((long)blockIdx.x * 256 + threadIdx.x) * 4;
    float4 v0 = *(const float4*)&t[i];
    float4 v1 = *(const float4*)&t[i + slice];
    float4 v2 = *(const float4*)&t[i + 2 * slice];
    float4 v3 = *(const float4*)&t[i + 3 * slice];
    float4 bv = *(const float4*)&bias[i & 511];
    float4 r;
    r.x = v0.x + v1.x + v2.x + v3.x + bv.x;
    r.y = v0.y + v1.y + v2.y + v3.y + bv.y;
    r.z = v0.z + v1.z + v2.z + v3.z + bv.z;
    r.w = v0.w + v1.w + v2.w + v3.w + bv.w;
    *(float4*)&o[i] = r;
}

// ---------------------------------------------------------------------------
// LayerNorm helpers (rows of 512, 256 threads, float2 per thread)
__device__ inline float2 block_reduce2(float a, float b) {
    __shared__ float sa[4], sb[4];
    #pragma unroll
    for (int off = 32; off; off >>= 1) {
        a += __shfl_down(a, off, 64);
        b += __shfl_down(b, off, 64);
    }
    __syncthreads();
    int w = threadIdx.x >> 6;
    if ((threadIdx.x & 63) == 0) { sa[w] = a; sb[w] = b; }
    __syncthreads();
    return make_float2(sa[0] + sa[1] + sa[2] + sa[3],
                       sb[0] + sb[1] + sb[2] + sb[3]);
}
__device__ inline float2 ln_pair(float2 v) {
    float2 s = block_reduce2(v.x + v.y, 0.f);
    float mu = s.x * (1.0f / 512.0f);
    float dx = v.x - mu, dy = v.y - mu;
    float2 q = block_reduce2(dx * dx + dy * dy, 0.f);
    float inv = rsqrtf(q.x * (1.0f / 512.0f) + 1e-5f);
    return make_float2(dx * inv, dy * inv);
}

// LN(sum of 4 slices + bias) -> fp32 + bf16
__global__ __launch_bounds__(256) void ln_dual4(const float* __restrict__ t,
                                                long slice,
                                                const float* __restrict__ bias,
                                                float* __restrict__ outf,
                                                unsigned short* __restrict__ outb) {
    long row = blockIdx.x;
    int c = threadIdx.x * 2;
    long i = row * 512 + c;
    float2 v0 = *(const float2*)&t[i];
    float2 v1 = *(const float2*)&t[i + slice];
    float2 v2 = *(const float2*)&t[i + 2 * slice];
    float2 v3 = *(const float2*)&t[i + 3 * slice];
    float2 bv = *(const float2*)&bias[c];
    float2 v = make_float2(v0.x + v1.x + v2.x + v3.x + bv.x,
                           v0.y + v1.y + v2.y + v3.y + bv.y);
    float2 o = ln_pair(v);
    *(float2*)&outf[i] = o;
    ushort2 ob; ob.x = f2b(o.x); ob.y = f2b(o.y);
    *(ushort2*)&outb[i] = ob;
}

// xs_next = LN(x_res + LN(sum of 4 ymlp slices)) -> fp32 + bf16
__global__ __launch_bounds__(256) void combine_dual4(
    const float* __restrict__ t, long slice, const float* __restrict__ xres,
    float* __restrict__ outf, unsigned short* __restrict__ outb) {
    long row = blockIdx.x;
    int c = threadIdx.x * 2;
    long i = row * 512 + c;
    float2 v0 = *(const float2*)&t[i];
    float2 v1 = *(const float2*)&t[i + slice];
    float2 v2 = *(const float2*)&t[i + 2 * slice];
    float2 v3 = *(const float2*)&t[i + 3 * slice];
    float2 y = make_float2(v0.x + v1.x + v2.x + v3.x,
                           v0.y + v1.y + v2.y + v3.y);
    float2 l = ln_pair(y);
    float2 r = *(const float2*)&xres[i];
    float2 z = make_float2(r.x + l.x, r.y + l.y);
    float2 o = ln_pair(z);
    *(float2*)&outf[i] = o;
    ushort2 ob; ob.x = f2b(o.x); ob.y = f2b(o.y);
    *(ushort2*)&outb[i] = ob;
}

// ---------------------------------------------------------------------------
extern "C" void kernel_launch(void* const* d_in, const int* in_sizes, int n_in,
                              void* d_out, int out_size, void* d_ws,
                              size_t ws_size, hipStream_t stream) {
    const float* x      = (const float*)d_in[0];
    const float* w_in   = (const float*)d_in[1];
    const float* b_in   = (const float*)d_in[2];
    const float* enc    = (const float*)d_in[3];
    const float* enc_v  = (const float*)d_in[4];
    const float* dec    = (const float*)d_in[5];
    const float* head_w = (const float*)d_in[6];
    const float* head_b = (const float*)d_in[7];
    float* out = (float*)d_out;

    // ---- workspace (~215 MB) ----
    char* w = (char*)d_ws;
    auto alloc = [&](size_t bytes) { void* p = (void*)w; w += bytes; return p; };
    unsigned short* w_inT = (unsigned short*)alloc((size_t)512 * 512 * 2);
    unsigned short* headT = (unsigned short*)alloc((size_t)512 * 512 * 2);
    unsigned short* encT  = (unsigned short*)alloc((size_t)NH_ * NL_ * D_ * 2);
    unsigned short* encvT = (unsigned short*)alloc((size_t)NH_ * NL_ * D_ * 2);
    unsigned short* decT  = (unsigned short*)alloc((size_t)D_ * HN_ * 2);
    unsigned short* xb    = (unsigned short*)alloc((size_t)BT_ * D_ * 2);
    float*          tmp   = (float*)alloc((size_t)4 * BT_ * D_ * 4);  // 4 K-slices
    float*          xsf0  = (float*)alloc((size_t)BT_ * D_ * 4);
    float*          xsf1  = (float*)alloc((size_t)BT_ * D_ * 4);
    unsigned short* xs_b  = (unsigned short*)alloc((size_t)BT_ * D_ * 2);
    unsigned short* xsT   = (unsigned short*)alloc((size_t)B_ * D_ * T_ * 2);
    unsigned short* xsp   = (unsigned short*)alloc((size_t)BT_ * HN_ * 2);
    unsigned short* qrh   = (unsigned short*)alloc((size_t)BT_ * HN_ * 2);
    unsigned short* qrT   = (unsigned short*)alloc((size_t)BT_ * HN_ * 2);
    unsigned short* Ct    = (unsigned short*)alloc((size_t)256 * 512 * 256 * 2); // 67 MB
    unsigned short* Sd    = (unsigned short*)alloc((size_t)256 * 128 * 128 * 2); //  8 MB
    unsigned short* ykv   = (unsigned short*)alloc((size_t)NH_ * BT_ * D_ * 2);
    const long SL = (long)BT_ * D_;   // split-K slice stride (elements)

    // ---- prep ----
    cast_b<<<BT_ * D_ / 1024, 256, 0, stream>>>(x, xb);
    trans_cast<<<dim3(16, 16, 1), 256, 0, stream>>>(w_in, 0, w_inT, 0, 512, 512);
    trans_cast<<<dim3(16, 16, 1), 256, 0, stream>>>(head_w, 0, headT, 0, 512, 512);
    trans_cast<<<dim3(8, 16, 8), 256, 0, stream>>>(enc, (long)D_ * NL_, encT,
                                                   (long)NL_ * D_, D_, NL_);
    trans_cast<<<dim3(8, 16, 8), 256, 0, stream>>>(enc_v, (long)D_ * NL_, encvT,
                                                   (long)NL_ * D_, D_, NL_);
    trans_cast<<<dim3(16, 64, 1), 256, 0, stream>>>(dec, 0, decT, 0, HN_, D_);

    // ---- xs = LN(x @ w_in + b_in)  (split-K=4) ----
    gemm64<false, false, false>
        <<<dim3(4, 64, 4), 256, 0, stream>>>(xb, D_, 128, w_inT, D_, 128, tmp,
                                             D_, SL, nullptr, BT_, D_, 128);
    ln_dual4<<<BT_, 256, 0, stream>>>(tmp, SL, b_in, xsf0, xs_b);
    trans_cast<<<dim3(16, 64, 2), 256, 0, stream>>>(xsf0, (long)T_ * D_, xsT,
                                                    (long)D_ * T_, T_, D_);

    float* xin = xsf0;
    float* xout = xsf1;
    for (int l = 0; l < 3; ++l) {
        // x_sparse + rope + both QR layouts, one kernel
        enc_rope<<<dim3(16, 64), 256, 0, stream>>>(xs_b, encT, xsp, qrh, qrT);
        // linear-attention state tiles: Ct[z][j] = X_j^T @ QR_j
        ct_gemm<<<dim3(16, 2, 128), 256, 0, stream>>>(xsT, qrT, Ct);
        // exclusive prefix over j (in place)
        prefix_k<<<dim3(16, 64), 256, 0, stream>>>(Ct);
        // diagonal strict scores
        sdiag<<<dim3(16, 16), 256, 0, stream>>>(qrh, Sd);
        // yKV = LN( QR_i @ P_i + Sd_i @ X_i )
        pxlin<<<dim3(16, 32), 256, 0, stream>>>(qrh, Ct, Sd, xsT, ykv);
        // xy = relu(yKV[h] @ enc_v[h]) * x_sparse — per-head batched
        gemm64<true, true, true>
            <<<dim3(2, 64, 8), 256, 0, stream>>>(
                ykv, D_, (long)BT_ * D_, encvT, D_, (long)NL_ * D_, xsp, HN_,
                NL_, xsp, BT_, NL_, D_);
        // yMLP = xy @ decoder  (split-K=4) -> fp32 slices
        gemm64<false, false, false>
            <<<dim3(4, 64, 4), 256, 0, stream>>>(
                xsp, HN_, 512, decT, HN_, 512, tmp, D_, SL, nullptr, BT_, D_,
                512);
        // xs = LN(x_res + LN(yMLP))
        combine_dual4<<<BT_, 256, 0, stream>>>(tmp, SL, xin, xout, xs_b);
        trans_cast<<<dim3(16, 64, 2), 256, 0, stream>>>(xout, (long)T_ * D_,
                                                        xsT, (long)D_ * T_, T_,
                                                        D_);
        float* t = xin; xin = xout; xout = t;
    }

    // logits = xs @ head_w + head_b  (split-K=4)
    gemm64<false, false, false>
        <<<dim3(4, 64, 4), 256, 0, stream>>>(xs_b, D_, 128, headT, D_, 128, tmp,
                                             D_, SL, nullptr, BT_, D_, 128);
    add_out4<<<BT_ * 512 / 1024, 256, 0, stream>>>(tmp, SL, head_b, out);
}